// Round 1
// baseline (1427.406 us; speedup 1.0000x reference)
//
#include <hip/hip_runtime.h>
#include <math.h>

#define B_ 8
#define S_ 2048
#define D_ 1024
#define H_ 16
#define A_ 4
#define DA_ 64
#define LN_EPS 1e-5f
#define SCALE 0.125f  // 1/sqrt(64)

// ---------------- workspace layout (bytes) ----------------
// partial : B*32*D fp32   = 1 MiB     @ 0
// idx     : B*A int       @ 1 MiB
// dist    : B*A fp32      @ 1 MiB + 1 KiB
// Q,K,V   : B*A*S*DA fp32 = 16 MiB each @ 2,18,34 MiB
// Ofin    : B*S*A*DA fp32 = 16 MiB   @ 50 MiB
static const size_t OFF_PARTIAL = 0;
static const size_t OFF_IDX     = (size_t)1 << 20;
static const size_t OFF_DIST    = ((size_t)1 << 20) + 1024;
static const size_t OFF_Q       = (size_t)2 << 20;
static const size_t QKV_BYTES   = (size_t)B_ * A_ * S_ * DA_ * 4;  // 16 MiB
static const size_t OFF_K       = OFF_Q + QKV_BYTES;
static const size_t OFF_V       = OFF_K + QKV_BYTES;
static const size_t OFF_OFIN    = OFF_V + QKV_BYTES;

// ---------------- kernel 1: column-mean partial reduce over S ----------------
// grid (32, B), block 256. partial[b][c][d] = sum of 64 rows.
__global__ __launch_bounds__(256) void k_partial(const float* __restrict__ x,
                                                 float* __restrict__ partial) {
  const int c = blockIdx.x, b = blockIdx.y, t = threadIdx.x;
  const float* xp = x + ((size_t)b * S_ + (size_t)c * 64) * D_;
  float a0 = 0.f, a1 = 0.f, a2 = 0.f, a3 = 0.f;
  for (int s = 0; s < 64; ++s) {
    const float* row = xp + (size_t)s * D_;
    a0 += row[t];
    a1 += row[256 + t];
    a2 += row[512 + t];
    a3 += row[768 + t];
  }
  float* pp = partial + ((size_t)b * 32 + c) * D_;
  pp[t] = a0; pp[256 + t] = a1; pp[512 + t] = a2; pp[768 + t] = a3;
}

// ---------------- kernel 2: xbar -> r -> LN -> softmax -> top4 ----------------
// grid B, block 256.
__global__ __launch_bounds__(256) void k_stats(const float* __restrict__ partial,
                                               const float* __restrict__ Wr,
                                               const float* __restrict__ br,
                                               const float* __restrict__ gamma,
                                               const float* __restrict__ beta,
                                               int* __restrict__ idx_out,
                                               float* __restrict__ dist_out) {
  __shared__ float xbar[D_];
  __shared__ float rsh[H_];
  const int b = blockIdx.x, t = threadIdx.x;
  #pragma unroll
  for (int j = 0; j < 4; ++j) {
    int d = j * 256 + t;
    float s = 0.f;
    for (int c = 0; c < 32; ++c) s += partial[((size_t)b * 32 + c) * D_ + d];
    xbar[d] = s * (1.0f / S_);
  }
  __syncthreads();
  const int w = t >> 6, lane = t & 63;
  #pragma unroll
  for (int i = 0; i < 4; ++i) {
    int h = w * 4 + i;
    float s = 0.f;
    #pragma unroll
    for (int j = 0; j < 16; ++j) {
      int d = j * 64 + lane;
      s += xbar[d] * Wr[d * H_ + h];
    }
    for (int off = 32; off; off >>= 1) s += __shfl_down(s, off);
    if (lane == 0) rsh[h] = s + br[h];
  }
  __syncthreads();
  if (t == 0) {
    float r[H_];
    float mu = 0.f;
    for (int h = 0; h < H_; ++h) { r[h] = rsh[h]; mu += r[h]; }
    mu *= (1.0f / H_);
    float var = 0.f;
    for (int h = 0; h < H_; ++h) { float d = r[h] - mu; var += d * d; }
    var *= (1.0f / H_);
    float inv = rsqrtf(var + LN_EPS);
    float rn[H_];
    float mx = -1e30f;
    for (int h = 0; h < H_; ++h) {
      rn[h] = (r[h] - mu) * inv * gamma[h] + beta[h];
      mx = fmaxf(mx, rn[h]);
    }
    float ex[H_];
    float sum = 0.f;
    for (int h = 0; h < H_; ++h) { ex[h] = expf(rn[h] - mx); sum += ex[h]; }
    // top-4 (strict > : ties pick lowest index, matches lax.top_k)
    int sel[A_];
    bool used[H_] = {false};
    for (int a = 0; a < A_; ++a) {
      int best = 0; float bv = -1.f;
      for (int h = 0; h < H_; ++h)
        if (!used[h] && ex[h] > bv) { bv = ex[h]; best = h; }
      used[best] = true; sel[a] = best;
    }
    // sort ascending
    for (int i = 0; i < A_; ++i)
      for (int j = i + 1; j < A_; ++j)
        if (sel[j] < sel[i]) { int tmp = sel[i]; sel[i] = sel[j]; sel[j] = tmp; }
    float invsum = 1.0f / sum;
    for (int a = 0; a < A_; ++a) {
      idx_out[b * A_ + a] = sel[a];
      dist_out[b * A_ + a] = ex[sel[a]] * invsum;
    }
  }
}

// ---------------- kernel 3: QKV projection for active heads ----------------
// grid (S/64, B*A, 3), block 256. 64x64 tile, K=1024 staged in 32-chunks.
__global__ __launch_bounds__(256) void k_qkv(const float* __restrict__ x,
                                             const float* __restrict__ Wq, const float* __restrict__ bq,
                                             const float* __restrict__ Wk, const float* __restrict__ bk,
                                             const float* __restrict__ Wv, const float* __restrict__ bv,
                                             const int* __restrict__ idx,
                                             float* __restrict__ Q, float* __restrict__ K,
                                             float* __restrict__ V) {
  __shared__ float xs[64][33];
  __shared__ float wsh[32][65];
  const int stile = blockIdx.x, ba = blockIdx.y, m = blockIdx.z;
  const int b = ba >> 2;
  const float* W    = (m == 0) ? Wq : (m == 1) ? Wk : Wv;
  const float* bias = (m == 0) ? bq : (m == 1) ? bk : bv;
  float* out        = (m == 0) ? Q  : (m == 1) ? K  : V;
  const int hcol = idx[ba] * DA_;
  const int t = threadIdx.x, tx = t & 15, ty = t >> 4;
  float acc[4][4] = {};
  const float* xbase = x + ((size_t)b * S_ + (size_t)stile * 64) * D_;
  for (int k0 = 0; k0 < D_; k0 += 32) {
    #pragma unroll
    for (int i = 0; i < 2; ++i) {
      int id = t + i * 256;            // 0..511
      int row = id >> 3, c4 = id & 7;  // 64 rows x 8 float4
      float4 v4 = *(const float4*)(xbase + (size_t)row * D_ + k0 + c4 * 4);
      xs[row][c4 * 4 + 0] = v4.x; xs[row][c4 * 4 + 1] = v4.y;
      xs[row][c4 * 4 + 2] = v4.z; xs[row][c4 * 4 + 3] = v4.w;
    }
    #pragma unroll
    for (int i = 0; i < 2; ++i) {
      int id = t + i * 256;
      int kr = id >> 4, c4 = id & 15;  // 32 rows x 16 float4
      float4 v4 = *(const float4*)(W + (size_t)(k0 + kr) * (H_ * DA_) + hcol + c4 * 4);
      wsh[kr][c4 * 4 + 0] = v4.x; wsh[kr][c4 * 4 + 1] = v4.y;
      wsh[kr][c4 * 4 + 2] = v4.z; wsh[kr][c4 * 4 + 3] = v4.w;
    }
    __syncthreads();
    #pragma unroll
    for (int kk = 0; kk < 32; ++kk) {
      float av[4], bv_[4];
      #pragma unroll
      for (int i = 0; i < 4; ++i) av[i] = xs[ty * 4 + i][kk];
      #pragma unroll
      for (int j = 0; j < 4; ++j) bv_[j] = wsh[kk][tx * 4 + j];
      #pragma unroll
      for (int i = 0; i < 4; ++i)
        #pragma unroll
        for (int j = 0; j < 4; ++j) acc[i][j] = fmaf(av[i], bv_[j], acc[i][j]);
    }
    __syncthreads();
  }
  float* obase = out + ((size_t)ba * S_ + (size_t)stile * 64) * DA_;
  #pragma unroll
  for (int i = 0; i < 4; ++i) {
    float4 v4;
    v4.x = acc[i][0] + bias[hcol + tx * 4 + 0];
    v4.y = acc[i][1] + bias[hcol + tx * 4 + 1];
    v4.z = acc[i][2] + bias[hcol + tx * 4 + 2];
    v4.w = acc[i][3] + bias[hcol + tx * 4 + 3];
    *(float4*)(obase + (size_t)(ty * 4 + i) * DA_ + tx * 4) = v4;
  }
}

// ---------------- kernel 4: flash attention per (b, active-head) ----------------
// grid (S/64, B*A), block 256. 64 Q-rows/block, K/V tiles of 64, online softmax.
// P tile reuses the K tile buffer (LDS = 3 x 64x65 fp32 = 48.8 KiB).
__global__ __launch_bounds__(256) void k_attn(const float* __restrict__ Q,
                                              const float* __restrict__ K,
                                              const float* __restrict__ V,
                                              const float* __restrict__ dist,
                                              float* __restrict__ Ofin) {
  __shared__ float qs[64][65];
  __shared__ float kp[64][65];  // K tile, then reused for P tile
  __shared__ float vs[64][65];
  const int qt = blockIdx.x, ba = blockIdx.y;
  const int b = ba >> 2, a = ba & 3;
  const int t = threadIdx.x, tx = t & 15, ty = t >> 4;
  const float* Qp = Q + ((size_t)ba * S_ + (size_t)qt * 64) * DA_;
  const float* Kp = K + (size_t)ba * S_ * DA_;
  const float* Vp = V + (size_t)ba * S_ * DA_;
  #pragma unroll
  for (int i = 0; i < 4; ++i) {
    int id = t + i * 256;
    int row = id >> 4, c4 = id & 15;
    float4 v4 = *(const float4*)(Qp + (size_t)row * DA_ + c4 * 4);
    qs[row][c4 * 4 + 0] = v4.x; qs[row][c4 * 4 + 1] = v4.y;
    qs[row][c4 * 4 + 2] = v4.z; qs[row][c4 * 4 + 3] = v4.w;
  }
  float m_i[4], l_i[4], o[4][4];
  #pragma unroll
  for (int i = 0; i < 4; ++i) {
    m_i[i] = -INFINITY; l_i[i] = 0.f;
    #pragma unroll
    for (int j = 0; j < 4; ++j) o[i][j] = 0.f;
  }

  for (int kt = 0; kt < 32; ++kt) {
    __syncthreads();  // previous P@V done before overwriting kp/vs
    #pragma unroll
    for (int i = 0; i < 4; ++i) {
      int id = t + i * 256;
      int row = id >> 4, c4 = id & 15;
      float4 k4 = *(const float4*)(Kp + (size_t)(kt * 64 + row) * DA_ + c4 * 4);
      kp[row][c4 * 4 + 0] = k4.x; kp[row][c4 * 4 + 1] = k4.y;
      kp[row][c4 * 4 + 2] = k4.z; kp[row][c4 * 4 + 3] = k4.w;
      float4 vv4 = *(const float4*)(Vp + (size_t)(kt * 64 + row) * DA_ + c4 * 4);
      vs[row][c4 * 4 + 0] = vv4.x; vs[row][c4 * 4 + 1] = vv4.y;
      vs[row][c4 * 4 + 2] = vv4.z; vs[row][c4 * 4 + 3] = vv4.w;
    }
    __syncthreads();
    // S-tile = Q K^T
    float sc[4][4] = {};
    #pragma unroll
    for (int kk = 0; kk < 64; ++kk) {
      float qv[4], kv[4];
      #pragma unroll
      for (int i = 0; i < 4; ++i) qv[i] = qs[ty * 4 + i][kk];
      #pragma unroll
      for (int j = 0; j < 4; ++j) kv[j] = kp[tx * 4 + j][kk];
      #pragma unroll
      for (int i = 0; i < 4; ++i)
        #pragma unroll
        for (int j = 0; j < 4; ++j) sc[i][j] = fmaf(qv[i], kv[j], sc[i][j]);
    }
    // online softmax (rows split across the 16-lane tx group)
    float alpha[4];
    #pragma unroll
    for (int i = 0; i < 4; ++i) {
      #pragma unroll
      for (int j = 0; j < 4; ++j) sc[i][j] *= SCALE;
      float rmax = fmaxf(fmaxf(sc[i][0], sc[i][1]), fmaxf(sc[i][2], sc[i][3]));
      for (int off = 1; off < 16; off <<= 1) rmax = fmaxf(rmax, __shfl_xor(rmax, off));
      float mnew = fmaxf(m_i[i], rmax);
      alpha[i] = expf(m_i[i] - mnew);
      m_i[i] = mnew;
      float rsum = 0.f;
      #pragma unroll
      for (int j = 0; j < 4; ++j) {
        float p = expf(sc[i][j] - mnew);
        sc[i][j] = p;
        rsum += p;
      }
      for (int off = 1; off < 16; off <<= 1) rsum += __shfl_xor(rsum, off);
      l_i[i] = l_i[i] * alpha[i] + rsum;
      #pragma unroll
      for (int j = 0; j < 4; ++j) o[i][j] *= alpha[i];
    }
    __syncthreads();  // everyone done reading kp as K
    #pragma unroll
    for (int i = 0; i < 4; ++i)
      #pragma unroll
      for (int j = 0; j < 4; ++j) kp[ty * 4 + i][tx * 4 + j] = sc[i][j];
    __syncthreads();  // P visible
    // O += P @ V
    #pragma unroll
    for (int tt = 0; tt < 64; ++tt) {
      float pv[4], vv[4];
      #pragma unroll
      for (int i = 0; i < 4; ++i) pv[i] = kp[ty * 4 + i][tt];
      #pragma unroll
      for (int j = 0; j < 4; ++j) vv[j] = vs[tt][tx * 4 + j];
      #pragma unroll
      for (int i = 0; i < 4; ++i)
        #pragma unroll
        for (int j = 0; j < 4; ++j) o[i][j] = fmaf(pv[i], vv[j], o[i][j]);
    }
  }
  const float dd = dist[ba];
  #pragma unroll
  for (int i = 0; i < 4; ++i) {
    float invl = dd / l_i[i];
    int row = qt * 64 + ty * 4 + i;
    float4 v4 = make_float4(o[i][0] * invl, o[i][1] * invl, o[i][2] * invl, o[i][3] * invl);
    *(float4*)(Ofin + ((size_t)b * S_ + row) * (A_ * DA_) + a * DA_ + tx * 4) = v4;
  }
}

// ---------------- kernel 5: output projection ----------------
// grid (D/64, B*S/64), block 256. (16384 x 256) @ (256 x 1024) + bo
__global__ __launch_bounds__(256) void k_oproj(const float* __restrict__ Of,
                                               const float* __restrict__ Wo,
                                               const float* __restrict__ bo,
                                               float* __restrict__ Z) {
  __shared__ float xs[64][33];
  __shared__ float wsh[32][65];
  const int nt = blockIdx.x, mt = blockIdx.y;
  const int t = threadIdx.x, tx = t & 15, ty = t >> 4;
  float acc[4][4] = {};
  const float* xbase = Of + (size_t)mt * 64 * (A_ * DA_);
  for (int k0 = 0; k0 < A_ * DA_; k0 += 32) {
    #pragma unroll
    for (int i = 0; i < 2; ++i) {
      int id = t + i * 256;
      int row = id >> 3, c4 = id & 7;
      float4 v4 = *(const float4*)(xbase + (size_t)row * (A_ * DA_) + k0 + c4 * 4);
      xs[row][c4 * 4 + 0] = v4.x; xs[row][c4 * 4 + 1] = v4.y;
      xs[row][c4 * 4 + 2] = v4.z; xs[row][c4 * 4 + 3] = v4.w;
    }
    #pragma unroll
    for (int i = 0; i < 2; ++i) {
      int id = t + i * 256;
      int kr = id >> 4, c4 = id & 15;
      float4 v4 = *(const float4*)(Wo + (size_t)(k0 + kr) * D_ + nt * 64 + c4 * 4);
      wsh[kr][c4 * 4 + 0] = v4.x; wsh[kr][c4 * 4 + 1] = v4.y;
      wsh[kr][c4 * 4 + 2] = v4.z; wsh[kr][c4 * 4 + 3] = v4.w;
    }
    __syncthreads();
    #pragma unroll
    for (int kk = 0; kk < 32; ++kk) {
      float av[4], bv_[4];
      #pragma unroll
      for (int i = 0; i < 4; ++i) av[i] = xs[ty * 4 + i][kk];
      #pragma unroll
      for (int j = 0; j < 4; ++j) bv_[j] = wsh[kk][tx * 4 + j];
      #pragma unroll
      for (int i = 0; i < 4; ++i)
        #pragma unroll
        for (int j = 0; j < 4; ++j) acc[i][j] = fmaf(av[i], bv_[j], acc[i][j]);
    }
    __syncthreads();
  }
  #pragma unroll
  for (int i = 0; i < 4; ++i) {
    float4 v4;
    v4.x = acc[i][0] + bo[nt * 64 + tx * 4 + 0];
    v4.y = acc[i][1] + bo[nt * 64 + tx * 4 + 1];
    v4.z = acc[i][2] + bo[nt * 64 + tx * 4 + 2];
    v4.w = acc[i][3] + bo[nt * 64 + tx * 4 + 3];
    *(float4*)(Z + (size_t)(mt * 64 + ty * 4 + i) * D_ + nt * 64 + tx * 4) = v4;
  }
}

extern "C" void kernel_launch(void* const* d_in, const int* in_sizes, int n_in,
                              void* d_out, int out_size, void* d_ws, size_t ws_size,
                              hipStream_t stream) {
  const float* x     = (const float*)d_in[0];
  const float* Wq    = (const float*)d_in[1];
  const float* bq    = (const float*)d_in[2];
  const float* Wk    = (const float*)d_in[3];
  const float* bk    = (const float*)d_in[4];
  const float* Wv    = (const float*)d_in[5];
  const float* bv    = (const float*)d_in[6];
  const float* Wr    = (const float*)d_in[7];
  const float* br    = (const float*)d_in[8];
  const float* gamma = (const float*)d_in[9];
  const float* beta  = (const float*)d_in[10];
  const float* Wo    = (const float*)d_in[11];
  const float* bo    = (const float*)d_in[12];
  float* Z = (float*)d_out;

  char* ws = (char*)d_ws;
  float* partial = (float*)(ws + OFF_PARTIAL);
  int*   idx     = (int*)(ws + OFF_IDX);
  float* dist    = (float*)(ws + OFF_DIST);
  float* Q       = (float*)(ws + OFF_Q);
  float* K       = (float*)(ws + OFF_K);
  float* V       = (float*)(ws + OFF_V);
  float* Ofin    = (float*)(ws + OFF_OFIN);

  k_partial<<<dim3(32, B_), 256, 0, stream>>>(x, partial);
  k_stats<<<B_, 256, 0, stream>>>(partial, Wr, br, gamma, beta, idx, dist);
  k_qkv<<<dim3(S_ / 64, B_ * A_, 3), 256, 0, stream>>>(x, Wq, bq, Wk, bk, Wv, bv, idx, Q, K, V);
  k_attn<<<dim3(S_ / 64, B_ * A_), 256, 0, stream>>>(Q, K, V, dist, Ofin);
  k_oproj<<<dim3(D_ / 64, (B_ * S_) / 64), 256, 0, stream>>>(Ofin, Wo, bo, Z);
}

// Round 2
// 801.039 us; speedup vs baseline: 1.7819x; 1.7819x over previous
//
#include <hip/hip_runtime.h>
#include <math.h>

#define B_ 8
#define S_ 2048
#define D_ 1024
#define H_ 16
#define A_ 4
#define DA_ 64
#define LN_EPS 1e-5f

typedef __bf16 bf16x8 __attribute__((ext_vector_type(8)));
typedef __bf16 bf16x4 __attribute__((ext_vector_type(4)));
typedef float f32x4 __attribute__((ext_vector_type(4)));
typedef unsigned short u16x8 __attribute__((ext_vector_type(8)));

// ---------------- workspace layout (bytes) ----------------
static const size_t OFF_PARTIAL = 0;                         // B*32*D fp32 = 1 MiB
static const size_t OFF_IDX     = (size_t)1 << 20;
static const size_t OFF_DIST    = ((size_t)1 << 20) + 1024;
static const size_t OFF_Q       = (size_t)2 << 20;           // bf16 QKV, 8 MiB each
static const size_t QKV_BYTES   = (size_t)B_ * A_ * S_ * DA_ * 2;
static const size_t OFF_K       = OFF_Q + QKV_BYTES;
static const size_t OFF_V       = OFF_K + QKV_BYTES;
static const size_t OFF_OFIN    = OFF_V + QKV_BYTES;         // fp32, 16 MiB

// ---------------- kernel 1: column-mean partial reduce over S ----------------
__global__ __launch_bounds__(256) void k_partial(const float* __restrict__ x,
                                                 float* __restrict__ partial) {
  const int c = blockIdx.x, b = blockIdx.y, t = threadIdx.x;
  const float* xp = x + ((size_t)b * S_ + (size_t)c * 64) * D_;
  float a0 = 0.f, a1 = 0.f, a2 = 0.f, a3 = 0.f;
  for (int s = 0; s < 64; ++s) {
    const float* row = xp + (size_t)s * D_;
    a0 += row[t]; a1 += row[256 + t]; a2 += row[512 + t]; a3 += row[768 + t];
  }
  float* pp = partial + ((size_t)b * 32 + c) * D_;
  pp[t] = a0; pp[256 + t] = a1; pp[512 + t] = a2; pp[768 + t] = a3;
}

// ---------------- kernel 2: xbar -> r -> LN -> softmax -> top4 ----------------
__global__ __launch_bounds__(256) void k_stats(const float* __restrict__ partial,
                                               const float* __restrict__ Wr,
                                               const float* __restrict__ br,
                                               const float* __restrict__ gamma,
                                               const float* __restrict__ beta,
                                               int* __restrict__ idx_out,
                                               float* __restrict__ dist_out) {
  __shared__ float xbar[D_];
  __shared__ float rsh[H_];
  const int b = blockIdx.x, t = threadIdx.x;
  #pragma unroll
  for (int j = 0; j < 4; ++j) {
    int d = j * 256 + t;
    float s = 0.f;
    for (int c = 0; c < 32; ++c) s += partial[((size_t)b * 32 + c) * D_ + d];
    xbar[d] = s * (1.0f / S_);
  }
  __syncthreads();
  const int w = t >> 6, lane = t & 63;
  #pragma unroll
  for (int i = 0; i < 4; ++i) {
    int h = w * 4 + i;
    float s = 0.f;
    #pragma unroll
    for (int j = 0; j < 16; ++j) {
      int d = j * 64 + lane;
      s += xbar[d] * Wr[d * H_ + h];
    }
    for (int off = 32; off; off >>= 1) s += __shfl_down(s, off);
    if (lane == 0) rsh[h] = s + br[h];
  }
  __syncthreads();
  if (t == 0) {
    float r[H_];
    float mu = 0.f;
    for (int h = 0; h < H_; ++h) { r[h] = rsh[h]; mu += r[h]; }
    mu *= (1.0f / H_);
    float var = 0.f;
    for (int h = 0; h < H_; ++h) { float d = r[h] - mu; var += d * d; }
    var *= (1.0f / H_);
    float inv = rsqrtf(var + LN_EPS);
    float rn[H_], ex[H_];
    float mx = -1e30f;
    for (int h = 0; h < H_; ++h) {
      rn[h] = (r[h] - mu) * inv * gamma[h] + beta[h];
      mx = fmaxf(mx, rn[h]);
    }
    float sum = 0.f;
    for (int h = 0; h < H_; ++h) { ex[h] = expf(rn[h] - mx); sum += ex[h]; }
    int sel[A_];
    bool used[H_] = {false};
    for (int a = 0; a < A_; ++a) {
      int best = 0; float bv = -1.f;
      for (int h = 0; h < H_; ++h)
        if (!used[h] && ex[h] > bv) { bv = ex[h]; best = h; }
      used[best] = true; sel[a] = best;
    }
    for (int i = 0; i < A_; ++i)
      for (int j = i + 1; j < A_; ++j)
        if (sel[j] < sel[i]) { int tmp = sel[i]; sel[i] = sel[j]; sel[j] = tmp; }
    float invsum = 1.0f / sum;
    for (int a = 0; a < A_; ++a) {
      idx_out[b * A_ + a] = sel[a];
      dist_out[b * A_ + a] = ex[sel[a]] * invsum;
    }
  }
}

// ---------------- kernel 3: QKV projection (fp32 compute, bf16 output) ----------------
// grid (S/64, B*A, 3), block 256. Q is pre-scaled by 1/sqrt(DA).
__global__ __launch_bounds__(256) void k_qkv(const float* __restrict__ x,
                                             const float* __restrict__ Wq, const float* __restrict__ bq,
                                             const float* __restrict__ Wk, const float* __restrict__ bk,
                                             const float* __restrict__ Wv, const float* __restrict__ bv,
                                             const int* __restrict__ idx,
                                             __bf16* __restrict__ Q, __bf16* __restrict__ K,
                                             __bf16* __restrict__ V) {
  __shared__ float xs[64][33];
  __shared__ float wsh[32][65];
  const int stile = blockIdx.x, ba = blockIdx.y, m = blockIdx.z;
  const int b = ba >> 2;
  const float* W    = (m == 0) ? Wq : (m == 1) ? Wk : Wv;
  const float* bias = (m == 0) ? bq : (m == 1) ? bk : bv;
  __bf16* out       = (m == 0) ? Q  : (m == 1) ? K  : V;
  const float scale = (m == 0) ? 0.125f : 1.0f;
  const int hcol = idx[ba] * DA_;
  const int t = threadIdx.x, tx = t & 15, ty = t >> 4;
  float acc[4][4] = {};
  const float* xbase = x + ((size_t)b * S_ + (size_t)stile * 64) * D_;
  for (int k0 = 0; k0 < D_; k0 += 32) {
    #pragma unroll
    for (int i = 0; i < 2; ++i) {
      int id = t + i * 256;
      int row = id >> 3, c4 = id & 7;
      float4 v4 = *(const float4*)(xbase + (size_t)row * D_ + k0 + c4 * 4);
      xs[row][c4 * 4 + 0] = v4.x; xs[row][c4 * 4 + 1] = v4.y;
      xs[row][c4 * 4 + 2] = v4.z; xs[row][c4 * 4 + 3] = v4.w;
    }
    #pragma unroll
    for (int i = 0; i < 2; ++i) {
      int id = t + i * 256;
      int kr = id >> 4, c4 = id & 15;
      float4 v4 = *(const float4*)(W + (size_t)(k0 + kr) * (H_ * DA_) + hcol + c4 * 4);
      wsh[kr][c4 * 4 + 0] = v4.x; wsh[kr][c4 * 4 + 1] = v4.y;
      wsh[kr][c4 * 4 + 2] = v4.z; wsh[kr][c4 * 4 + 3] = v4.w;
    }
    __syncthreads();
    #pragma unroll
    for (int kk = 0; kk < 32; ++kk) {
      float av[4], bv_[4];
      #pragma unroll
      for (int i = 0; i < 4; ++i) av[i] = xs[ty * 4 + i][kk];
      #pragma unroll
      for (int j = 0; j < 4; ++j) bv_[j] = wsh[kk][tx * 4 + j];
      #pragma unroll
      for (int i = 0; i < 4; ++i)
        #pragma unroll
        for (int j = 0; j < 4; ++j) acc[i][j] = fmaf(av[i], bv_[j], acc[i][j]);
    }
    __syncthreads();
  }
  __bf16* obase = out + ((size_t)ba * S_ + (size_t)stile * 64) * DA_;
  #pragma unroll
  for (int i = 0; i < 4; ++i) {
    bf16x4 v4b;
    #pragma unroll
    for (int j = 0; j < 4; ++j)
      v4b[j] = (__bf16)((acc[i][j] + bias[hcol + tx * 4 + j]) * scale);
    *(bf16x4*)(obase + (size_t)(ty * 4 + i) * DA_ + tx * 4) = v4b;
  }
}

// ---------------- kernel 4: flash attention, bf16 MFMA 16x16x32 ----------------
// grid (S/128, B*A), block 256 (4 waves). Wave owns 32 Q-rows (2 M-frags),
// N covers 64 (4 N-frags). K/V tiles of 64 rows; Q,K LDS chunk-XOR swizzled;
// V transposed in LDS (stride 72 u16); P via wave-local LDS (stride 72 u16).
__global__ __launch_bounds__(256) void k_attn_mfma(const __bf16* __restrict__ Qg,
                                                   const __bf16* __restrict__ Kg,
                                                   const __bf16* __restrict__ Vg,
                                                   const float* __restrict__ dist,
                                                   float* __restrict__ Ofin) {
  __shared__ unsigned short Qs[128 * 64];   // swizzled row-major [row][chunk^row&7]
  __shared__ unsigned short Ks[64 * 64];    // swizzled
  __shared__ unsigned short Vt[64 * 72];    // [da][kv], padded
  __shared__ unsigned short Ps[128 * 72];   // [row][kv], padded, wave-local

  const int qt = blockIdx.x, ba = blockIdx.y;
  const int b = ba >> 2, a = ba & 3;
  const int t = threadIdx.x;
  const int w = t >> 6, l = t & 63, x = l & 15, g = l >> 4;

  const unsigned short* Qgu = (const unsigned short*)Qg;
  const unsigned short* Kgu = (const unsigned short*)Kg;
  const unsigned short* Vgu = (const unsigned short*)Vg;

  // ---- stage Q tile (128 x 64), chunk-XOR swizzle ----
  {
    const size_t qbase = ((size_t)ba * S_ + (size_t)qt * 128) * DA_;
    #pragma unroll
    for (int i = 0; i < 4; ++i) {
      int row = (t >> 3) + 32 * i;
      int ch = t & 7;
      u16x8 v = *(const u16x8*)(Qgu + qbase + (size_t)row * 64 + ch * 8);
      *(u16x8*)&Qs[row * 64 + ((ch ^ (row & 7)) << 3)] = v;
    }
  }
  __syncthreads();

  // ---- hoist Q fragments: qf[mf][ks], A-frag = Q[row=x+16mf+32w][k=8g+j+32ks] ----
  bf16x8 qf[2][2];
  #pragma unroll
  for (int mf = 0; mf < 2; ++mf)
    #pragma unroll
    for (int ks = 0; ks < 2; ++ks) {
      int row = w * 32 + mf * 16 + x;
      int ch = (g + 4 * ks) ^ (row & 7);
      qf[mf][ks] = *(const bf16x8*)&Qs[row * 64 + (ch << 3)];
    }

  f32x4 o_[2][4];
  float m_[2][4], l_[2][4];
  #pragma unroll
  for (int mf = 0; mf < 2; ++mf)
    #pragma unroll
    for (int r = 0; r < 4; ++r) { m_[mf][r] = -INFINITY; l_[mf][r] = 0.f; }
  #pragma unroll
  for (int mf = 0; mf < 2; ++mf)
    #pragma unroll
    for (int nf = 0; nf < 4; ++nf) o_[mf][nf] = (f32x4){0.f, 0.f, 0.f, 0.f};

  const size_t kvbase = (size_t)ba * S_ * DA_;

  for (int kt = 0; kt < 32; ++kt) {
    __syncthreads();  // previous PV reads done before restaging
    // ---- stage K tile (64 x 64), swizzled ----
    #pragma unroll
    for (int i = 0; i < 2; ++i) {
      int row = (t >> 3) + 32 * i;
      int ch = t & 7;
      u16x8 v = *(const u16x8*)(Kgu + kvbase + (size_t)(kt * 64 + row) * 64 + ch * 8);
      *(u16x8*)&Ks[row * 64 + ((ch ^ (row & 7)) << 3)] = v;
    }
    // ---- stage V transposed: Vt[da][kv] ----
    {
      int kvp = t >> 3;          // kv pair 0..31
      int dab = (t & 7) * 8;     // da base
      u16x8 v0 = *(const u16x8*)(Vgu + kvbase + (size_t)(kt * 64 + 2 * kvp) * 64 + dab);
      u16x8 v1 = *(const u16x8*)(Vgu + kvbase + (size_t)(kt * 64 + 2 * kvp + 1) * 64 + dab);
      #pragma unroll
      for (int j = 0; j < 8; ++j) {
        unsigned int u = (unsigned int)v0[j] | ((unsigned int)v1[j] << 16);
        *(unsigned int*)&Vt[(dab + j) * 72 + 2 * kvp] = u;
      }
    }
    __syncthreads();

    // ---- QK^T: s_[mf][nf] over rows (4g+r+16mf+32w), cols (kv = x+16nf) ----
    f32x4 s_[2][4];
    #pragma unroll
    for (int mf = 0; mf < 2; ++mf)
      #pragma unroll
      for (int nf = 0; nf < 4; ++nf) s_[mf][nf] = (f32x4){0.f, 0.f, 0.f, 0.f};
    #pragma unroll
    for (int ks = 0; ks < 2; ++ks) {
      bf16x8 kf[4];
      #pragma unroll
      for (int nf = 0; nf < 4; ++nf) {
        int kvrow = nf * 16 + x;
        int ch = (g + 4 * ks) ^ (kvrow & 7);
        kf[nf] = *(const bf16x8*)&Ks[kvrow * 64 + (ch << 3)];
      }
      #pragma unroll
      for (int mf = 0; mf < 2; ++mf)
        #pragma unroll
        for (int nf = 0; nf < 4; ++nf)
          s_[mf][nf] = __builtin_amdgcn_mfma_f32_16x16x32_bf16(qf[mf][ks], kf[nf], s_[mf][nf], 0, 0, 0);
    }

    // ---- online softmax (rows live across the 16 x-lanes) ----
    #pragma unroll
    for (int mf = 0; mf < 2; ++mf) {
      #pragma unroll
      for (int r = 0; r < 4; ++r) {
        float mx = fmaxf(fmaxf(s_[mf][0][r], s_[mf][1][r]), fmaxf(s_[mf][2][r], s_[mf][3][r]));
        mx = fmaxf(mx, __shfl_xor(mx, 1));
        mx = fmaxf(mx, __shfl_xor(mx, 2));
        mx = fmaxf(mx, __shfl_xor(mx, 4));
        mx = fmaxf(mx, __shfl_xor(mx, 8));
        float mnew = fmaxf(m_[mf][r], mx);
        float al = __expf(m_[mf][r] - mnew);
        m_[mf][r] = mnew;
        float rs = 0.f;
        #pragma unroll
        for (int nf = 0; nf < 4; ++nf) {
          float p = __expf(s_[mf][nf][r] - mnew);
          s_[mf][nf][r] = p;
          rs += p;
        }
        rs += __shfl_xor(rs, 1);
        rs += __shfl_xor(rs, 2);
        rs += __shfl_xor(rs, 4);
        rs += __shfl_xor(rs, 8);
        l_[mf][r] = l_[mf][r] * al + rs;
        #pragma unroll
        for (int nf = 0; nf < 4; ++nf) o_[mf][nf][r] *= al;
      }
    }

    // ---- P -> LDS (wave-local rows), bf16 ----
    #pragma unroll
    for (int mf = 0; mf < 2; ++mf)
      #pragma unroll
      for (int nf = 0; nf < 4; ++nf)
        #pragma unroll
        for (int r = 0; r < 4; ++r) {
          int row = w * 32 + mf * 16 + 4 * g + r;
          int col = nf * 16 + x;
          __bf16 pb = (__bf16)s_[mf][nf][r];
          Ps[row * 72 + col] = __builtin_bit_cast(unsigned short, pb);
        }

    // ---- PV: O += P @ V ----
    #pragma unroll
    for (int ks = 0; ks < 2; ++ks) {
      bf16x8 pf[2];
      #pragma unroll
      for (int mf = 0; mf < 2; ++mf) {
        int prow = w * 32 + mf * 16 + x;
        pf[mf] = *(const bf16x8*)&Ps[prow * 72 + (g * 8 + ks * 32)];
      }
      bf16x8 vf[4];
      #pragma unroll
      for (int nf = 0; nf < 4; ++nf) {
        int darow = nf * 16 + x;
        vf[nf] = *(const bf16x8*)&Vt[darow * 72 + (g * 8 + ks * 32)];
      }
      #pragma unroll
      for (int mf = 0; mf < 2; ++mf)
        #pragma unroll
        for (int nf = 0; nf < 4; ++nf)
          o_[mf][nf] = __builtin_amdgcn_mfma_f32_16x16x32_bf16(pf[mf], vf[nf], o_[mf][nf], 0, 0, 0);
    }
  }

  // ---- epilogue: scale by dist/l, write Ofin fp32 [b][s][a*64+da] ----
  const float dd = dist[ba];
  #pragma unroll
  for (int mf = 0; mf < 2; ++mf) {
    float inv[4];
    #pragma unroll
    for (int r = 0; r < 4; ++r) inv[r] = dd / l_[mf][r];
    #pragma unroll
    for (int nf = 0; nf < 4; ++nf)
      #pragma unroll
      for (int r = 0; r < 4; ++r) {
        int row = qt * 128 + w * 32 + mf * 16 + 4 * g + r;
        int col = nf * 16 + x;
        Ofin[((size_t)b * S_ + row) * (A_ * DA_) + a * DA_ + col] = o_[mf][nf][r] * inv[r];
      }
  }
}

// ---------------- kernel 5: output projection (fp32) ----------------
__global__ __launch_bounds__(256) void k_oproj(const float* __restrict__ Of,
                                               const float* __restrict__ Wo,
                                               const float* __restrict__ bo,
                                               float* __restrict__ Z) {
  __shared__ float xs[64][33];
  __shared__ float wsh[32][65];
  const int nt = blockIdx.x, mt = blockIdx.y;
  const int t = threadIdx.x, tx = t & 15, ty = t >> 4;
  float acc[4][4] = {};
  const float* xbase = Of + (size_t)mt * 64 * (A_ * DA_);
  for (int k0 = 0; k0 < A_ * DA_; k0 += 32) {
    #pragma unroll
    for (int i = 0; i < 2; ++i) {
      int id = t + i * 256;
      int row = id >> 3, c4 = id & 7;
      float4 v4 = *(const float4*)(xbase + (size_t)row * (A_ * DA_) + k0 + c4 * 4);
      xs[row][c4 * 4 + 0] = v4.x; xs[row][c4 * 4 + 1] = v4.y;
      xs[row][c4 * 4 + 2] = v4.z; xs[row][c4 * 4 + 3] = v4.w;
    }
    #pragma unroll
    for (int i = 0; i < 2; ++i) {
      int id = t + i * 256;
      int kr = id >> 4, c4 = id & 15;
      float4 v4 = *(const float4*)(Wo + (size_t)(k0 + kr) * D_ + nt * 64 + c4 * 4);
      wsh[kr][c4 * 4 + 0] = v4.x; wsh[kr][c4 * 4 + 1] = v4.y;
      wsh[kr][c4 * 4 + 2] = v4.z; wsh[kr][c4 * 4 + 3] = v4.w;
    }
    __syncthreads();
    #pragma unroll
    for (int kk = 0; kk < 32; ++kk) {
      float av[4], bv_[4];
      #pragma unroll
      for (int i = 0; i < 4; ++i) av[i] = xs[ty * 4 + i][kk];
      #pragma unroll
      for (int j = 0; j < 4; ++j) bv_[j] = wsh[kk][tx * 4 + j];
      #pragma unroll
      for (int i = 0; i < 4; ++i)
        #pragma unroll
        for (int j = 0; j < 4; ++j) acc[i][j] = fmaf(av[i], bv_[j], acc[i][j]);
    }
    __syncthreads();
  }
  #pragma unroll
  for (int i = 0; i < 4; ++i) {
    float4 v4;
    v4.x = acc[i][0] + bo[nt * 64 + tx * 4 + 0];
    v4.y = acc[i][1] + bo[nt * 64 + tx * 4 + 1];
    v4.z = acc[i][2] + bo[nt * 64 + tx * 4 + 2];
    v4.w = acc[i][3] + bo[nt * 64 + tx * 4 + 3];
    *(float4*)(Z + (size_t)(mt * 64 + ty * 4 + i) * D_ + nt * 64 + tx * 4) = v4;
  }
}

extern "C" void kernel_launch(void* const* d_in, const int* in_sizes, int n_in,
                              void* d_out, int out_size, void* d_ws, size_t ws_size,
                              hipStream_t stream) {
  const float* x     = (const float*)d_in[0];
  const float* Wq    = (const float*)d_in[1];
  const float* bq    = (const float*)d_in[2];
  const float* Wk    = (const float*)d_in[3];
  const float* bk    = (const float*)d_in[4];
  const float* Wv    = (const float*)d_in[5];
  const float* bv    = (const float*)d_in[6];
  const float* Wr    = (const float*)d_in[7];
  const float* br    = (const float*)d_in[8];
  const float* gamma = (const float*)d_in[9];
  const float* beta  = (const float*)d_in[10];
  const float* Wo    = (const float*)d_in[11];
  const float* bo    = (const float*)d_in[12];
  float* Z = (float*)d_out;

  char* ws = (char*)d_ws;
  float*  partial = (float*)(ws + OFF_PARTIAL);
  int*    idx     = (int*)(ws + OFF_IDX);
  float*  dist    = (float*)(ws + OFF_DIST);
  __bf16* Q       = (__bf16*)(ws + OFF_Q);
  __bf16* K       = (__bf16*)(ws + OFF_K);
  __bf16* V       = (__bf16*)(ws + OFF_V);
  float*  Ofin    = (float*)(ws + OFF_OFIN);

  k_partial<<<dim3(32, B_), 256, 0, stream>>>(x, partial);
  k_stats<<<B_, 256, 0, stream>>>(partial, Wr, br, gamma, beta, idx, dist);
  k_qkv<<<dim3(S_ / 64, B_ * A_, 3), 256, 0, stream>>>(x, Wq, bq, Wk, bk, Wv, bv, idx, Q, K, V);
  k_attn_mfma<<<dim3(S_ / 128, B_ * A_), 256, 0, stream>>>(Q, K, V, dist, Ofin);
  k_oproj<<<dim3(D_ / 64, (B_ * S_) / 64), 256, 0, stream>>>(Ofin, Wo, bo, Z);
}

// Round 3
// 397.052 us; speedup vs baseline: 3.5950x; 2.0175x over previous
//
#include <hip/hip_runtime.h>
#include <math.h>

#define B_ 8
#define S_ 2048
#define D_ 1024
#define H_ 16
#define A_ 4
#define DA_ 64
#define LN_EPS 1e-5f

typedef __bf16 bf16x8 __attribute__((ext_vector_type(8)));
typedef __bf16 bf16x4 __attribute__((ext_vector_type(4)));
typedef float f32x4 __attribute__((ext_vector_type(4)));
typedef unsigned short u16x8 __attribute__((ext_vector_type(8)));

// ---------------- workspace layout (bytes) ----------------
// partial 1 MiB @0 ; idx/dist @1 MiB ; xb (bf16 x) 32 MiB @2 MiB (Ofin aliases it);
// Wt (bf16, [3][n][k]) 6 MiB @34 MiB ; Q/K/V bf16 8 MiB each @40/48/56 MiB. total 64 MiB.
static const size_t OFF_PARTIAL = 0;
static const size_t OFF_IDX     = (size_t)1 << 20;
static const size_t OFF_DIST    = ((size_t)1 << 20) + 1024;
static const size_t OFF_XB      = (size_t)2 << 20;
static const size_t OFF_OFIN    = OFF_XB;                    // aliased: xb dead after k_qkv
static const size_t OFF_WT      = (size_t)34 << 20;
static const size_t OFF_Q       = (size_t)40 << 20;
static const size_t OFF_K       = (size_t)48 << 20;
static const size_t OFF_V       = (size_t)56 << 20;

// ---------------- kernel 1: column-sum partial over S + bf16 convert ----------------
// grid (32, B), block 256. partial[b][c][d] = sum of 64 rows; xb = bf16(x).
__global__ __launch_bounds__(256) void k_partial(const float* __restrict__ x,
                                                 float* __restrict__ partial,
                                                 __bf16* __restrict__ xb) {
  const int c = blockIdx.x, b = blockIdx.y, t = threadIdx.x;
  const size_t base = ((size_t)b * S_ + (size_t)c * 64) * D_;
  f32x4 acc = {0.f, 0.f, 0.f, 0.f};
  for (int s = 0; s < 64; ++s) {
    f32x4 v = *(const f32x4*)(x + base + (size_t)s * D_ + 4 * t);
    acc += v;
    bf16x4 o;
    #pragma unroll
    for (int j = 0; j < 4; ++j) o[j] = (__bf16)v[j];
    *(bf16x4*)(xb + base + (size_t)s * D_ + 4 * t) = o;
  }
  *(f32x4*)(partial + ((size_t)b * 32 + c) * D_ + 4 * t) = acc;
}

// ---------------- kernel 1b: transpose weights to bf16 [m][n][k] ----------------
// grid (16 n-tiles, 16 k-tiles, 3), block 256.
__global__ __launch_bounds__(256) void k_wt(const float* __restrict__ Wq,
                                            const float* __restrict__ Wk,
                                            const float* __restrict__ Wv,
                                            __bf16* __restrict__ Wt) {
  __shared__ float tsh[64][65];
  const int n0 = blockIdx.x * 64, k0 = blockIdx.y * 64, z = blockIdx.z;
  const float* W = (z == 0) ? Wq : (z == 1) ? Wk : Wv;
  const int t = threadIdx.x;
  #pragma unroll
  for (int i = 0; i < 4; ++i) {
    int r = i * 16 + (t >> 4), c = (t & 15) * 4;
    f32x4 v = *(const f32x4*)(W + (size_t)(k0 + r) * (H_ * DA_) + n0 + c);
    tsh[r][c + 0] = v[0]; tsh[r][c + 1] = v[1]; tsh[r][c + 2] = v[2]; tsh[r][c + 3] = v[3];
  }
  __syncthreads();
  #pragma unroll
  for (int i = 0; i < 4; ++i) {
    int n = i * 16 + (t >> 4), kc = (t & 15) * 4;
    bf16x4 o;
    #pragma unroll
    for (int j = 0; j < 4; ++j) o[j] = (__bf16)tsh[kc + j][n];
    *(bf16x4*)(Wt + (size_t)z * 1048576 + (size_t)(n0 + n) * 1024 + k0 + kc) = o;
  }
}

// ---------------- kernel 2: xbar -> r -> LN -> softmax -> top4 ----------------
__global__ __launch_bounds__(256) void k_stats(const float* __restrict__ partial,
                                               const float* __restrict__ Wr,
                                               const float* __restrict__ br,
                                               const float* __restrict__ gamma,
                                               const float* __restrict__ beta,
                                               int* __restrict__ idx_out,
                                               float* __restrict__ dist_out) {
  __shared__ float xbar[D_];
  __shared__ float rsh[H_];
  const int b = blockIdx.x, t = threadIdx.x;
  #pragma unroll
  for (int j = 0; j < 4; ++j) {
    int d = j * 256 + t;
    float s = 0.f;
    for (int c = 0; c < 32; ++c) s += partial[((size_t)b * 32 + c) * D_ + d];
    xbar[d] = s * (1.0f / S_);
  }
  __syncthreads();
  const int w = t >> 6, lane = t & 63;
  #pragma unroll
  for (int i = 0; i < 4; ++i) {
    int h = w * 4 + i;
    float s = 0.f;
    #pragma unroll
    for (int j = 0; j < 16; ++j) {
      int d = j * 64 + lane;
      s += xbar[d] * Wr[d * H_ + h];
    }
    for (int off = 32; off; off >>= 1) s += __shfl_down(s, off);
    if (lane == 0) rsh[h] = s + br[h];
  }
  __syncthreads();
  if (t == 0) {
    float r[H_];
    float mu = 0.f;
    for (int h = 0; h < H_; ++h) { r[h] = rsh[h]; mu += r[h]; }
    mu *= (1.0f / H_);
    float var = 0.f;
    for (int h = 0; h < H_; ++h) { float d = r[h] - mu; var += d * d; }
    var *= (1.0f / H_);
    float inv = rsqrtf(var + LN_EPS);
    float rn[H_], ex[H_];
    float mx = -1e30f;
    for (int h = 0; h < H_; ++h) {
      rn[h] = (r[h] - mu) * inv * gamma[h] + beta[h];
      mx = fmaxf(mx, rn[h]);
    }
    float sum = 0.f;
    for (int h = 0; h < H_; ++h) { ex[h] = expf(rn[h] - mx); sum += ex[h]; }
    int sel[A_];
    bool used[H_] = {false};
    for (int a = 0; a < A_; ++a) {
      int best = 0; float bv = -1.f;
      for (int h = 0; h < H_; ++h)
        if (!used[h] && ex[h] > bv) { bv = ex[h]; best = h; }
      used[best] = true; sel[a] = best;
    }
    for (int i = 0; i < A_; ++i)
      for (int j = i + 1; j < A_; ++j)
        if (sel[j] < sel[i]) { int tmp = sel[i]; sel[i] = sel[j]; sel[j] = tmp; }
    float invsum = 1.0f / sum;
    for (int a = 0; a < A_; ++a) {
      idx_out[b * A_ + a] = sel[a];
      dist_out[b * A_ + a] = ex[sel[a]] * invsum;
    }
  }
}

// ---------------- kernel 3: QKV projection, bf16 MFMA ----------------
// grid (S/128, B*A), block 256 (4 waves). Tile 128(M) x 192(N = Q|K|V 64 each),
// BK=64. Wave owns 64x96 (4 M-frag x 6 N-frag). Q pre-scaled by 1/8.
__global__ __launch_bounds__(256) void k_qkv_mfma(const __bf16* __restrict__ xb,
                                                  const __bf16* __restrict__ Wt,
                                                  const float* __restrict__ bq,
                                                  const float* __restrict__ bk,
                                                  const float* __restrict__ bv,
                                                  const int* __restrict__ idx,
                                                  __bf16* __restrict__ Q,
                                                  __bf16* __restrict__ K,
                                                  __bf16* __restrict__ V) {
  __shared__ unsigned short As[128][72];
  __shared__ unsigned short Bs[192][72];
  const int qt = blockIdx.x, ba = blockIdx.y;
  const int b = ba >> 2;
  const int head64 = idx[ba] * 64;
  const int t = threadIdx.x;
  const int w = t >> 6, l = t & 63, x = l & 15, g = l >> 4;
  const int MO = (w >> 1) * 64, NO = (w & 1) * 96;

  const unsigned short* xbu = (const unsigned short*)xb;
  const unsigned short* Wtu = (const unsigned short*)Wt;
  const size_t xbase = ((size_t)b * S_ + (size_t)qt * 128) * D_;

  f32x4 acc[4][6];
  #pragma unroll
  for (int mf = 0; mf < 4; ++mf)
    #pragma unroll
    for (int nf = 0; nf < 6; ++nf) acc[mf][nf] = (f32x4){0.f, 0.f, 0.f, 0.f};

  for (int k0 = 0; k0 < D_; k0 += 64) {
    // stage A: 128 x 64 bf16
    #pragma unroll
    for (int i = 0; i < 4; ++i) {
      int id = t + 256 * i;
      int row = id >> 3, ch = id & 7;
      u16x8 v = *(const u16x8*)(xbu + xbase + (size_t)row * D_ + k0 + ch * 8);
      *(u16x8*)&As[row][ch * 8] = v;
    }
    // stage B: 192 x 64 bf16 (rows 0..63 = Wq slice, 64..127 = Wk, 128..191 = Wv)
    #pragma unroll
    for (int i = 0; i < 6; ++i) {
      int id = t + 256 * i;
      int row = id >> 3, ch = id & 7;
      int m = row >> 6, nn = row & 63;
      u16x8 v = *(const u16x8*)(Wtu + (size_t)m * 1048576 +
                                (size_t)(head64 + nn) * 1024 + k0 + ch * 8);
      *(u16x8*)&Bs[row][ch * 8] = v;
    }
    __syncthreads();
    #pragma unroll
    for (int ks = 0; ks < 2; ++ks) {
      bf16x8 af[4], bfr[6];
      #pragma unroll
      for (int mf = 0; mf < 4; ++mf)
        af[mf] = *(const bf16x8*)&As[MO + mf * 16 + x][ks * 32 + g * 8];
      #pragma unroll
      for (int nf = 0; nf < 6; ++nf)
        bfr[nf] = *(const bf16x8*)&Bs[NO + nf * 16 + x][ks * 32 + g * 8];
      #pragma unroll
      for (int mf = 0; mf < 4; ++mf)
        #pragma unroll
        for (int nf = 0; nf < 6; ++nf)
          acc[mf][nf] = __builtin_amdgcn_mfma_f32_16x16x32_bf16(af[mf], bfr[nf], acc[mf][nf], 0, 0, 0);
    }
    __syncthreads();
  }

  // epilogue: bias, Q-scale, bf16 store
  #pragma unroll
  for (int nf = 0; nf < 6; ++nf) {
    const int n = NO + nf * 16;          // wave-uniform
    const int m = n >> 6;                // 0=Q 1=K 2=V, wave-uniform
    const float* bias = (m == 0) ? bq : (m == 1) ? bk : bv;
    __bf16* out = (m == 0) ? Q : (m == 1) ? K : V;
    const float sc = (m == 0) ? 0.125f : 1.0f;
    const int nn = (n & 63) + x;
    const float bval = bias[head64 + nn];
    #pragma unroll
    for (int mf = 0; mf < 4; ++mf)
      #pragma unroll
      for (int r = 0; r < 4; ++r) {
        int srow = qt * 128 + MO + mf * 16 + 4 * g + r;
        float val = (acc[mf][nf][r] + bval) * sc;
        out[((size_t)ba * S_ + srow) * DA_ + nn] = (__bf16)val;
      }
  }
}

// ---------------- kernel 4: flash attention, bf16 MFMA 16x16x32 ----------------
// grid (S/128, B*A), block 256 (4 waves). (unchanged from round 2, refcheck'd)
__global__ __launch_bounds__(256) void k_attn_mfma(const __bf16* __restrict__ Qg,
                                                   const __bf16* __restrict__ Kg,
                                                   const __bf16* __restrict__ Vg,
                                                   const float* __restrict__ dist,
                                                   float* __restrict__ Ofin) {
  __shared__ unsigned short Qs[128 * 64];
  __shared__ unsigned short Ks[64 * 64];
  __shared__ unsigned short Vt[64 * 72];
  __shared__ unsigned short Ps[128 * 72];

  const int qt = blockIdx.x, ba = blockIdx.y;
  const int b = ba >> 2, a = ba & 3;
  const int t = threadIdx.x;
  const int w = t >> 6, l = t & 63, x = l & 15, g = l >> 4;

  const unsigned short* Qgu = (const unsigned short*)Qg;
  const unsigned short* Kgu = (const unsigned short*)Kg;
  const unsigned short* Vgu = (const unsigned short*)Vg;

  {
    const size_t qbase = ((size_t)ba * S_ + (size_t)qt * 128) * DA_;
    #pragma unroll
    for (int i = 0; i < 4; ++i) {
      int row = (t >> 3) + 32 * i;
      int ch = t & 7;
      u16x8 v = *(const u16x8*)(Qgu + qbase + (size_t)row * 64 + ch * 8);
      *(u16x8*)&Qs[row * 64 + ((ch ^ (row & 7)) << 3)] = v;
    }
  }
  __syncthreads();

  bf16x8 qf[2][2];
  #pragma unroll
  for (int mf = 0; mf < 2; ++mf)
    #pragma unroll
    for (int ks = 0; ks < 2; ++ks) {
      int row = w * 32 + mf * 16 + x;
      int ch = (g + 4 * ks) ^ (row & 7);
      qf[mf][ks] = *(const bf16x8*)&Qs[row * 64 + (ch << 3)];
    }

  f32x4 o_[2][4];
  float m_[2][4], l_[2][4];
  #pragma unroll
  for (int mf = 0; mf < 2; ++mf)
    #pragma unroll
    for (int r = 0; r < 4; ++r) { m_[mf][r] = -INFINITY; l_[mf][r] = 0.f; }
  #pragma unroll
  for (int mf = 0; mf < 2; ++mf)
    #pragma unroll
    for (int nf = 0; nf < 4; ++nf) o_[mf][nf] = (f32x4){0.f, 0.f, 0.f, 0.f};

  const size_t kvbase = (size_t)ba * S_ * DA_;

  for (int kt = 0; kt < 32; ++kt) {
    __syncthreads();
    #pragma unroll
    for (int i = 0; i < 2; ++i) {
      int row = (t >> 3) + 32 * i;
      int ch = t & 7;
      u16x8 v = *(const u16x8*)(Kgu + kvbase + (size_t)(kt * 64 + row) * 64 + ch * 8);
      *(u16x8*)&Ks[row * 64 + ((ch ^ (row & 7)) << 3)] = v;
    }
    {
      int kvp = t >> 3;
      int dab = (t & 7) * 8;
      u16x8 v0 = *(const u16x8*)(Vgu + kvbase + (size_t)(kt * 64 + 2 * kvp) * 64 + dab);
      u16x8 v1 = *(const u16x8*)(Vgu + kvbase + (size_t)(kt * 64 + 2 * kvp + 1) * 64 + dab);
      #pragma unroll
      for (int j = 0; j < 8; ++j) {
        unsigned int u = (unsigned int)v0[j] | ((unsigned int)v1[j] << 16);
        *(unsigned int*)&Vt[(dab + j) * 72 + 2 * kvp] = u;
      }
    }
    __syncthreads();

    f32x4 s_[2][4];
    #pragma unroll
    for (int mf = 0; mf < 2; ++mf)
      #pragma unroll
      for (int nf = 0; nf < 4; ++nf) s_[mf][nf] = (f32x4){0.f, 0.f, 0.f, 0.f};
    #pragma unroll
    for (int ks = 0; ks < 2; ++ks) {
      bf16x8 kf[4];
      #pragma unroll
      for (int nf = 0; nf < 4; ++nf) {
        int kvrow = nf * 16 + x;
        int ch = (g + 4 * ks) ^ (kvrow & 7);
        kf[nf] = *(const bf16x8*)&Ks[kvrow * 64 + (ch << 3)];
      }
      #pragma unroll
      for (int mf = 0; mf < 2; ++mf)
        #pragma unroll
        for (int nf = 0; nf < 4; ++nf)
          s_[mf][nf] = __builtin_amdgcn_mfma_f32_16x16x32_bf16(qf[mf][ks], kf[nf], s_[mf][nf], 0, 0, 0);
    }

    #pragma unroll
    for (int mf = 0; mf < 2; ++mf) {
      #pragma unroll
      for (int r = 0; r < 4; ++r) {
        float mx = fmaxf(fmaxf(s_[mf][0][r], s_[mf][1][r]), fmaxf(s_[mf][2][r], s_[mf][3][r]));
        mx = fmaxf(mx, __shfl_xor(mx, 1));
        mx = fmaxf(mx, __shfl_xor(mx, 2));
        mx = fmaxf(mx, __shfl_xor(mx, 4));
        mx = fmaxf(mx, __shfl_xor(mx, 8));
        float mnew = fmaxf(m_[mf][r], mx);
        float al = __expf(m_[mf][r] - mnew);
        m_[mf][r] = mnew;
        float rs = 0.f;
        #pragma unroll
        for (int nf = 0; nf < 4; ++nf) {
          float p = __expf(s_[mf][nf][r] - mnew);
          s_[mf][nf][r] = p;
          rs += p;
        }
        rs += __shfl_xor(rs, 1);
        rs += __shfl_xor(rs, 2);
        rs += __shfl_xor(rs, 4);
        rs += __shfl_xor(rs, 8);
        l_[mf][r] = l_[mf][r] * al + rs;
        #pragma unroll
        for (int nf = 0; nf < 4; ++nf) o_[mf][nf][r] *= al;
      }
    }

    #pragma unroll
    for (int mf = 0; mf < 2; ++mf)
      #pragma unroll
      for (int nf = 0; nf < 4; ++nf)
        #pragma unroll
        for (int r = 0; r < 4; ++r) {
          int row = w * 32 + mf * 16 + 4 * g + r;
          int col = nf * 16 + x;
          __bf16 pb = (__bf16)s_[mf][nf][r];
          Ps[row * 72 + col] = __builtin_bit_cast(unsigned short, pb);
        }

    #pragma unroll
    for (int ks = 0; ks < 2; ++ks) {
      bf16x8 pf[2];
      #pragma unroll
      for (int mf = 0; mf < 2; ++mf) {
        int prow = w * 32 + mf * 16 + x;
        pf[mf] = *(const bf16x8*)&Ps[prow * 72 + (g * 8 + ks * 32)];
      }
      bf16x8 vf[4];
      #pragma unroll
      for (int nf = 0; nf < 4; ++nf) {
        int darow = nf * 16 + x;
        vf[nf] = *(const bf16x8*)&Vt[darow * 72 + (g * 8 + ks * 32)];
      }
      #pragma unroll
      for (int mf = 0; mf < 2; ++mf)
        #pragma unroll
        for (int nf = 0; nf < 4; ++nf)
          o_[mf][nf] = __builtin_amdgcn_mfma_f32_16x16x32_bf16(pf[mf], vf[nf], o_[mf][nf], 0, 0, 0);
    }
  }

  const float dd = dist[ba];
  #pragma unroll
  for (int mf = 0; mf < 2; ++mf) {
    float inv[4];
    #pragma unroll
    for (int r = 0; r < 4; ++r) inv[r] = dd / l_[mf][r];
    #pragma unroll
    for (int nf = 0; nf < 4; ++nf)
      #pragma unroll
      for (int r = 0; r < 4; ++r) {
        int row = qt * 128 + w * 32 + mf * 16 + 4 * g + r;
        int col = nf * 16 + x;
        Ofin[((size_t)b * S_ + row) * (A_ * DA_) + a * DA_ + col] = o_[mf][nf][r] * inv[r];
      }
  }
}

// ---------------- kernel 5: output projection (fp32) ----------------
__global__ __launch_bounds__(256) void k_oproj(const float* __restrict__ Of,
                                               const float* __restrict__ Wo,
                                               const float* __restrict__ bo,
                                               float* __restrict__ Z) {
  __shared__ float xs[64][33];
  __shared__ float wsh[32][65];
  const int nt = blockIdx.x, mt = blockIdx.y;
  const int t = threadIdx.x, tx = t & 15, ty = t >> 4;
  float acc[4][4] = {};
  const float* xbase = Of + (size_t)mt * 64 * (A_ * DA_);
  for (int k0 = 0; k0 < A_ * DA_; k0 += 32) {
    #pragma unroll
    for (int i = 0; i < 2; ++i) {
      int id = t + i * 256;
      int row = id >> 3, c4 = id & 7;
      float4 v4 = *(const float4*)(xbase + (size_t)row * (A_ * DA_) + k0 + c4 * 4);
      xs[row][c4 * 4 + 0] = v4.x; xs[row][c4 * 4 + 1] = v4.y;
      xs[row][c4 * 4 + 2] = v4.z; xs[row][c4 * 4 + 3] = v4.w;
    }
    #pragma unroll
    for (int i = 0; i < 2; ++i) {
      int id = t + i * 256;
      int kr = id >> 4, c4 = id & 15;
      float4 v4 = *(const float4*)(Wo + (size_t)(k0 + kr) * D_ + nt * 64 + c4 * 4);
      wsh[kr][c4 * 4 + 0] = v4.x; wsh[kr][c4 * 4 + 1] = v4.y;
      wsh[kr][c4 * 4 + 2] = v4.z; wsh[kr][c4 * 4 + 3] = v4.w;
    }
    __syncthreads();
    #pragma unroll
    for (int kk = 0; kk < 32; ++kk) {
      float av[4], bv_[4];
      #pragma unroll
      for (int i = 0; i < 4; ++i) av[i] = xs[ty * 4 + i][kk];
      #pragma unroll
      for (int j = 0; j < 4; ++j) bv_[j] = wsh[kk][tx * 4 + j];
      #pragma unroll
      for (int i = 0; i < 4; ++i)
        #pragma unroll
        for (int j = 0; j < 4; ++j) acc[i][j] = fmaf(av[i], bv_[j], acc[i][j]);
    }
    __syncthreads();
  }
  #pragma unroll
  for (int i = 0; i < 4; ++i) {
    float4 v4;
    v4.x = acc[i][0] + bo[nt * 64 + tx * 4 + 0];
    v4.y = acc[i][1] + bo[nt * 64 + tx * 4 + 1];
    v4.z = acc[i][2] + bo[nt * 64 + tx * 4 + 2];
    v4.w = acc[i][3] + bo[nt * 64 + tx * 4 + 3];
    *(float4*)(Z + (size_t)(mt * 64 + ty * 4 + i) * D_ + nt * 64 + tx * 4) = v4;
  }
}

extern "C" void kernel_launch(void* const* d_in, const int* in_sizes, int n_in,
                              void* d_out, int out_size, void* d_ws, size_t ws_size,
                              hipStream_t stream) {
  const float* x     = (const float*)d_in[0];
  const float* Wq    = (const float*)d_in[1];
  const float* bq    = (const float*)d_in[2];
  const float* Wk    = (const float*)d_in[3];
  const float* bk    = (const float*)d_in[4];
  const float* Wv    = (const float*)d_in[5];
  const float* bv    = (const float*)d_in[6];
  const float* Wr    = (const float*)d_in[7];
  const float* br    = (const float*)d_in[8];
  const float* gamma = (const float*)d_in[9];
  const float* beta  = (const float*)d_in[10];
  const float* Wo    = (const float*)d_in[11];
  const float* bo    = (const float*)d_in[12];
  float* Z = (float*)d_out;

  char* ws = (char*)d_ws;
  float*  partial = (float*)(ws + OFF_PARTIAL);
  int*    idx     = (int*)(ws + OFF_IDX);
  float*  dist    = (float*)(ws + OFF_DIST);
  __bf16* xb      = (__bf16*)(ws + OFF_XB);
  __bf16* Wt      = (__bf16*)(ws + OFF_WT);
  __bf16* Q       = (__bf16*)(ws + OFF_Q);
  __bf16* K       = (__bf16*)(ws + OFF_K);
  __bf16* V       = (__bf16*)(ws + OFF_V);
  float*  Ofin    = (float*)(ws + OFF_OFIN);

  k_partial<<<dim3(32, B_), 256, 0, stream>>>(x, partial, xb);
  k_wt<<<dim3(16, 16, 3), 256, 0, stream>>>(Wq, Wk, Wv, Wt);
  k_stats<<<B_, 256, 0, stream>>>(partial, Wr, br, gamma, beta, idx, dist);
  k_qkv_mfma<<<dim3(S_ / 128, B_ * A_), 256, 0, stream>>>(xb, Wt, bq, bk, bv, idx, Q, K, V);
  k_attn_mfma<<<dim3(S_ / 128, B_ * A_), 256, 0, stream>>>(Q, K, V, dist, Ofin);
  k_oproj<<<dim3(D_ / 64, (B_ * S_) / 64), 256, 0, stream>>>(Ofin, Wo, bo, Z);
}

// Round 4
// 274.374 us; speedup vs baseline: 5.2024x; 1.4471x over previous
//
#include <hip/hip_runtime.h>
#include <math.h>

#define B_ 8
#define S_ 2048
#define D_ 1024
#define H_ 16
#define A_ 4
#define DA_ 64
#define LN_EPS 1e-5f

typedef __bf16 bf16x8 __attribute__((ext_vector_type(8)));
typedef __bf16 bf16x4 __attribute__((ext_vector_type(4)));
typedef float f32x4 __attribute__((ext_vector_type(4)));
typedef unsigned short u16x8 __attribute__((ext_vector_type(8)));

// ---------------- workspace layout (bytes) ----------------
// partial 1 MiB @0 ; idx/dist @1 MiB ; WoT bf16 512 KiB @1.5 MiB ;
// xb (bf16 x) 32 MiB @2 MiB (Ofin bf16 aliases it) ; Wt 6 MiB @34 MiB ;
// Q/K/V bf16 8 MiB each @40/48/56 MiB. total 64 MiB.
static const size_t OFF_PARTIAL = 0;
static const size_t OFF_IDX     = (size_t)1 << 20;
static const size_t OFF_DIST    = ((size_t)1 << 20) + 1024;
static const size_t OFF_WOT     = ((size_t)1 << 20) + ((size_t)1 << 19);
static const size_t OFF_XB      = (size_t)2 << 20;
static const size_t OFF_OFIN    = OFF_XB;                    // aliased: xb dead after k_qkv
static const size_t OFF_WT      = (size_t)34 << 20;
static const size_t OFF_Q       = (size_t)40 << 20;
static const size_t OFF_K       = (size_t)48 << 20;
static const size_t OFF_V       = (size_t)56 << 20;

// ---------------- kernel 1: column-sum partial over S + bf16 convert ----------------
__global__ __launch_bounds__(256) void k_partial(const float* __restrict__ x,
                                                 float* __restrict__ partial,
                                                 __bf16* __restrict__ xb) {
  const int c = blockIdx.x, b = blockIdx.y, t = threadIdx.x;
  const size_t base = ((size_t)b * S_ + (size_t)c * 64) * D_;
  f32x4 acc = {0.f, 0.f, 0.f, 0.f};
  for (int s = 0; s < 64; ++s) {
    f32x4 v = *(const f32x4*)(x + base + (size_t)s * D_ + 4 * t);
    acc += v;
    bf16x4 o;
    #pragma unroll
    for (int j = 0; j < 4; ++j) o[j] = (__bf16)v[j];
    *(bf16x4*)(xb + base + (size_t)s * D_ + 4 * t) = o;
  }
  *(f32x4*)(partial + ((size_t)b * 32 + c) * D_ + 4 * t) = acc;
}

// ---------------- kernel 1b: transpose QKV weights to bf16 [m][n][k] ----------------
__global__ __launch_bounds__(256) void k_wt(const float* __restrict__ Wq,
                                            const float* __restrict__ Wk,
                                            const float* __restrict__ Wv,
                                            __bf16* __restrict__ Wt) {
  __shared__ float tsh[64][65];
  const int n0 = blockIdx.x * 64, k0 = blockIdx.y * 64, z = blockIdx.z;
  const float* W = (z == 0) ? Wq : (z == 1) ? Wk : Wv;
  const int t = threadIdx.x;
  #pragma unroll
  for (int i = 0; i < 4; ++i) {
    int r = i * 16 + (t >> 4), c = (t & 15) * 4;
    f32x4 v = *(const f32x4*)(W + (size_t)(k0 + r) * (H_ * DA_) + n0 + c);
    tsh[r][c + 0] = v[0]; tsh[r][c + 1] = v[1]; tsh[r][c + 2] = v[2]; tsh[r][c + 3] = v[3];
  }
  __syncthreads();
  #pragma unroll
  for (int i = 0; i < 4; ++i) {
    int n = i * 16 + (t >> 4), kc = (t & 15) * 4;
    bf16x4 o;
    #pragma unroll
    for (int j = 0; j < 4; ++j) o[j] = (__bf16)tsh[kc + j][n];
    *(bf16x4*)(Wt + (size_t)z * 1048576 + (size_t)(n0 + n) * 1024 + k0 + kc) = o;
  }
}

// ---------------- kernel 1c: transpose Wo [256][1024] -> WoT bf16 [1024][256] ----------------
__global__ __launch_bounds__(256) void k_wto(const float* __restrict__ Wo,
                                             __bf16* __restrict__ WoT) {
  __shared__ float tsh[64][65];
  const int n0 = blockIdx.x * 64, k0 = blockIdx.y * 64;
  const int t = threadIdx.x;
  #pragma unroll
  for (int i = 0; i < 4; ++i) {
    int r = i * 16 + (t >> 4), c = (t & 15) * 4;
    f32x4 v = *(const f32x4*)(Wo + (size_t)(k0 + r) * D_ + n0 + c);
    tsh[r][c + 0] = v[0]; tsh[r][c + 1] = v[1]; tsh[r][c + 2] = v[2]; tsh[r][c + 3] = v[3];
  }
  __syncthreads();
  #pragma unroll
  for (int i = 0; i < 4; ++i) {
    int n = i * 16 + (t >> 4), kc = (t & 15) * 4;
    bf16x4 o;
    #pragma unroll
    for (int j = 0; j < 4; ++j) o[j] = (__bf16)tsh[kc + j][n];
    *(bf16x4*)(WoT + (size_t)(n0 + n) * (A_ * DA_) + k0 + kc) = o;
  }
}

// ---------------- kernel 2: xbar -> r -> LN -> softmax -> top4 ----------------
__global__ __launch_bounds__(256) void k_stats(const float* __restrict__ partial,
                                               const float* __restrict__ Wr,
                                               const float* __restrict__ br,
                                               const float* __restrict__ gamma,
                                               const float* __restrict__ beta,
                                               int* __restrict__ idx_out,
                                               float* __restrict__ dist_out) {
  __shared__ float xbar[D_];
  __shared__ float rsh[H_];
  const int b = blockIdx.x, t = threadIdx.x;
  #pragma unroll
  for (int j = 0; j < 4; ++j) {
    int d = j * 256 + t;
    float s = 0.f;
    for (int c = 0; c < 32; ++c) s += partial[((size_t)b * 32 + c) * D_ + d];
    xbar[d] = s * (1.0f / S_);
  }
  __syncthreads();
  const int w = t >> 6, lane = t & 63;
  #pragma unroll
  for (int i = 0; i < 4; ++i) {
    int h = w * 4 + i;
    float s = 0.f;
    #pragma unroll
    for (int j = 0; j < 16; ++j) {
      int d = j * 64 + lane;
      s += xbar[d] * Wr[d * H_ + h];
    }
    for (int off = 32; off; off >>= 1) s += __shfl_down(s, off);
    if (lane == 0) rsh[h] = s + br[h];
  }
  __syncthreads();
  if (t == 0) {
    float r[H_];
    float mu = 0.f;
    for (int h = 0; h < H_; ++h) { r[h] = rsh[h]; mu += r[h]; }
    mu *= (1.0f / H_);
    float var = 0.f;
    for (int h = 0; h < H_; ++h) { float d = r[h] - mu; var += d * d; }
    var *= (1.0f / H_);
    float inv = rsqrtf(var + LN_EPS);
    float rn[H_], ex[H_];
    float mx = -1e30f;
    for (int h = 0; h < H_; ++h) {
      rn[h] = (r[h] - mu) * inv * gamma[h] + beta[h];
      mx = fmaxf(mx, rn[h]);
    }
    float sum = 0.f;
    for (int h = 0; h < H_; ++h) { ex[h] = expf(rn[h] - mx); sum += ex[h]; }
    int sel[A_];
    bool used[H_] = {false};
    for (int a = 0; a < A_; ++a) {
      int best = 0; float bv = -1.f;
      for (int h = 0; h < H_; ++h)
        if (!used[h] && ex[h] > bv) { bv = ex[h]; best = h; }
      used[best] = true; sel[a] = best;
    }
    for (int i = 0; i < A_; ++i)
      for (int j = i + 1; j < A_; ++j)
        if (sel[j] < sel[i]) { int tmp = sel[i]; sel[i] = sel[j]; sel[j] = tmp; }
    float invsum = 1.0f / sum;
    for (int a = 0; a < A_; ++a) {
      idx_out[b * A_ + a] = sel[a];
      dist_out[b * A_ + a] = ex[sel[a]] * invsum;
    }
  }
}

// ---------------- kernel 3: QKV projection, bf16 MFMA ----------------
__global__ __launch_bounds__(256) void k_qkv_mfma(const __bf16* __restrict__ xb,
                                                  const __bf16* __restrict__ Wt,
                                                  const float* __restrict__ bq,
                                                  const float* __restrict__ bk,
                                                  const float* __restrict__ bv,
                                                  const int* __restrict__ idx,
                                                  __bf16* __restrict__ Q,
                                                  __bf16* __restrict__ K,
                                                  __bf16* __restrict__ V) {
  __shared__ unsigned short As[128][72];
  __shared__ unsigned short Bs[192][72];
  const int qt = blockIdx.x, ba = blockIdx.y;
  const int b = ba >> 2;
  const int head64 = idx[ba] * 64;
  const int t = threadIdx.x;
  const int w = t >> 6, l = t & 63, x = l & 15, g = l >> 4;
  const int MO = (w >> 1) * 64, NO = (w & 1) * 96;

  const unsigned short* xbu = (const unsigned short*)xb;
  const unsigned short* Wtu = (const unsigned short*)Wt;
  const size_t xbase = ((size_t)b * S_ + (size_t)qt * 128) * D_;

  f32x4 acc[4][6];
  #pragma unroll
  for (int mf = 0; mf < 4; ++mf)
    #pragma unroll
    for (int nf = 0; nf < 6; ++nf) acc[mf][nf] = (f32x4){0.f, 0.f, 0.f, 0.f};

  for (int k0 = 0; k0 < D_; k0 += 64) {
    #pragma unroll
    for (int i = 0; i < 4; ++i) {
      int id = t + 256 * i;
      int row = id >> 3, ch = id & 7;
      u16x8 v = *(const u16x8*)(xbu + xbase + (size_t)row * D_ + k0 + ch * 8);
      *(u16x8*)&As[row][ch * 8] = v;
    }
    #pragma unroll
    for (int i = 0; i < 6; ++i) {
      int id = t + 256 * i;
      int row = id >> 3, ch = id & 7;
      int m = row >> 6, nn = row & 63;
      u16x8 v = *(const u16x8*)(Wtu + (size_t)m * 1048576 +
                                (size_t)(head64 + nn) * 1024 + k0 + ch * 8);
      *(u16x8*)&Bs[row][ch * 8] = v;
    }
    __syncthreads();
    #pragma unroll
    for (int ks = 0; ks < 2; ++ks) {
      bf16x8 af[4], bfr[6];
      #pragma unroll
      for (int mf = 0; mf < 4; ++mf)
        af[mf] = *(const bf16x8*)&As[MO + mf * 16 + x][ks * 32 + g * 8];
      #pragma unroll
      for (int nf = 0; nf < 6; ++nf)
        bfr[nf] = *(const bf16x8*)&Bs[NO + nf * 16 + x][ks * 32 + g * 8];
      #pragma unroll
      for (int mf = 0; mf < 4; ++mf)
        #pragma unroll
        for (int nf = 0; nf < 6; ++nf)
          acc[mf][nf] = __builtin_amdgcn_mfma_f32_16x16x32_bf16(af[mf], bfr[nf], acc[mf][nf], 0, 0, 0);
    }
    __syncthreads();
  }

  #pragma unroll
  for (int nf = 0; nf < 6; ++nf) {
    const int n = NO + nf * 16;
    const int m = n >> 6;
    const float* bias = (m == 0) ? bq : (m == 1) ? bk : bv;
    __bf16* out = (m == 0) ? Q : (m == 1) ? K : V;
    const float sc = (m == 0) ? 0.125f : 1.0f;
    const int nn = (n & 63) + x;
    const float bval = bias[head64 + nn];
    #pragma unroll
    for (int mf = 0; mf < 4; ++mf)
      #pragma unroll
      for (int r = 0; r < 4; ++r) {
        int srow = qt * 128 + MO + mf * 16 + 4 * g + r;
        float val = (acc[mf][nf][r] + bval) * sc;
        out[((size_t)ba * S_ + srow) * DA_ + nn] = (__bf16)val;
      }
  }
}

// ---------------- kernel 4: flash attention, bf16 MFMA 16x16x32 ----------------
// (same as round 3, but Ofin is now bf16)
__global__ __launch_bounds__(256) void k_attn_mfma(const __bf16* __restrict__ Qg,
                                                   const __bf16* __restrict__ Kg,
                                                   const __bf16* __restrict__ Vg,
                                                   const float* __restrict__ dist,
                                                   __bf16* __restrict__ Ofin) {
  __shared__ unsigned short Qs[128 * 64];
  __shared__ unsigned short Ks[64 * 64];
  __shared__ unsigned short Vt[64 * 72];
  __shared__ unsigned short Ps[128 * 72];

  const int qt = blockIdx.x, ba = blockIdx.y;
  const int b = ba >> 2, a = ba & 3;
  const int t = threadIdx.x;
  const int w = t >> 6, l = t & 63, x = l & 15, g = l >> 4;

  const unsigned short* Qgu = (const unsigned short*)Qg;
  const unsigned short* Kgu = (const unsigned short*)Kg;
  const unsigned short* Vgu = (const unsigned short*)Vg;

  {
    const size_t qbase = ((size_t)ba * S_ + (size_t)qt * 128) * DA_;
    #pragma unroll
    for (int i = 0; i < 4; ++i) {
      int row = (t >> 3) + 32 * i;
      int ch = t & 7;
      u16x8 v = *(const u16x8*)(Qgu + qbase + (size_t)row * 64 + ch * 8);
      *(u16x8*)&Qs[row * 64 + ((ch ^ (row & 7)) << 3)] = v;
    }
  }
  __syncthreads();

  bf16x8 qf[2][2];
  #pragma unroll
  for (int mf = 0; mf < 2; ++mf)
    #pragma unroll
    for (int ks = 0; ks < 2; ++ks) {
      int row = w * 32 + mf * 16 + x;
      int ch = (g + 4 * ks) ^ (row & 7);
      qf[mf][ks] = *(const bf16x8*)&Qs[row * 64 + (ch << 3)];
    }

  f32x4 o_[2][4];
  float m_[2][4], l_[2][4];
  #pragma unroll
  for (int mf = 0; mf < 2; ++mf)
    #pragma unroll
    for (int r = 0; r < 4; ++r) { m_[mf][r] = -INFINITY; l_[mf][r] = 0.f; }
  #pragma unroll
  for (int mf = 0; mf < 2; ++mf)
    #pragma unroll
    for (int nf = 0; nf < 4; ++nf) o_[mf][nf] = (f32x4){0.f, 0.f, 0.f, 0.f};

  const size_t kvbase = (size_t)ba * S_ * DA_;

  for (int kt = 0; kt < 32; ++kt) {
    __syncthreads();
    #pragma unroll
    for (int i = 0; i < 2; ++i) {
      int row = (t >> 3) + 32 * i;
      int ch = t & 7;
      u16x8 v = *(const u16x8*)(Kgu + kvbase + (size_t)(kt * 64 + row) * 64 + ch * 8);
      *(u16x8*)&Ks[row * 64 + ((ch ^ (row & 7)) << 3)] = v;
    }
    {
      int kvp = t >> 3;
      int dab = (t & 7) * 8;
      u16x8 v0 = *(const u16x8*)(Vgu + kvbase + (size_t)(kt * 64 + 2 * kvp) * 64 + dab);
      u16x8 v1 = *(const u16x8*)(Vgu + kvbase + (size_t)(kt * 64 + 2 * kvp + 1) * 64 + dab);
      #pragma unroll
      for (int j = 0; j < 8; ++j) {
        unsigned int u = (unsigned int)v0[j] | ((unsigned int)v1[j] << 16);
        *(unsigned int*)&Vt[(dab + j) * 72 + 2 * kvp] = u;
      }
    }
    __syncthreads();

    f32x4 s_[2][4];
    #pragma unroll
    for (int mf = 0; mf < 2; ++mf)
      #pragma unroll
      for (int nf = 0; nf < 4; ++nf) s_[mf][nf] = (f32x4){0.f, 0.f, 0.f, 0.f};
    #pragma unroll
    for (int ks = 0; ks < 2; ++ks) {
      bf16x8 kf[4];
      #pragma unroll
      for (int nf = 0; nf < 4; ++nf) {
        int kvrow = nf * 16 + x;
        int ch = (g + 4 * ks) ^ (kvrow & 7);
        kf[nf] = *(const bf16x8*)&Ks[kvrow * 64 + (ch << 3)];
      }
      #pragma unroll
      for (int mf = 0; mf < 2; ++mf)
        #pragma unroll
        for (int nf = 0; nf < 4; ++nf)
          s_[mf][nf] = __builtin_amdgcn_mfma_f32_16x16x32_bf16(qf[mf][ks], kf[nf], s_[mf][nf], 0, 0, 0);
    }

    #pragma unroll
    for (int mf = 0; mf < 2; ++mf) {
      #pragma unroll
      for (int r = 0; r < 4; ++r) {
        float mx = fmaxf(fmaxf(s_[mf][0][r], s_[mf][1][r]), fmaxf(s_[mf][2][r], s_[mf][3][r]));
        mx = fmaxf(mx, __shfl_xor(mx, 1));
        mx = fmaxf(mx, __shfl_xor(mx, 2));
        mx = fmaxf(mx, __shfl_xor(mx, 4));
        mx = fmaxf(mx, __shfl_xor(mx, 8));
        float mnew = fmaxf(m_[mf][r], mx);
        float al = __expf(m_[mf][r] - mnew);
        m_[mf][r] = mnew;
        float rs = 0.f;
        #pragma unroll
        for (int nf = 0; nf < 4; ++nf) {
          float p = __expf(s_[mf][nf][r] - mnew);
          s_[mf][nf][r] = p;
          rs += p;
        }
        rs += __shfl_xor(rs, 1);
        rs += __shfl_xor(rs, 2);
        rs += __shfl_xor(rs, 4);
        rs += __shfl_xor(rs, 8);
        l_[mf][r] = l_[mf][r] * al + rs;
        #pragma unroll
        for (int nf = 0; nf < 4; ++nf) o_[mf][nf][r] *= al;
      }
    }

    #pragma unroll
    for (int mf = 0; mf < 2; ++mf)
      #pragma unroll
      for (int nf = 0; nf < 4; ++nf)
        #pragma unroll
        for (int r = 0; r < 4; ++r) {
          int row = w * 32 + mf * 16 + 4 * g + r;
          int col = nf * 16 + x;
          __bf16 pb = (__bf16)s_[mf][nf][r];
          Ps[row * 72 + col] = __builtin_bit_cast(unsigned short, pb);
        }

    #pragma unroll
    for (int ks = 0; ks < 2; ++ks) {
      bf16x8 pf[2];
      #pragma unroll
      for (int mf = 0; mf < 2; ++mf) {
        int prow = w * 32 + mf * 16 + x;
        pf[mf] = *(const bf16x8*)&Ps[prow * 72 + (g * 8 + ks * 32)];
      }
      bf16x8 vf[4];
      #pragma unroll
      for (int nf = 0; nf < 4; ++nf) {
        int darow = nf * 16 + x;
        vf[nf] = *(const bf16x8*)&Vt[darow * 72 + (g * 8 + ks * 32)];
      }
      #pragma unroll
      for (int mf = 0; mf < 2; ++mf)
        #pragma unroll
        for (int nf = 0; nf < 4; ++nf)
          o_[mf][nf] = __builtin_amdgcn_mfma_f32_16x16x32_bf16(pf[mf], vf[nf], o_[mf][nf], 0, 0, 0);
    }
  }

  const float dd = dist[ba];
  #pragma unroll
  for (int mf = 0; mf < 2; ++mf) {
    float inv[4];
    #pragma unroll
    for (int r = 0; r < 4; ++r) inv[r] = dd / l_[mf][r];
    #pragma unroll
    for (int nf = 0; nf < 4; ++nf)
      #pragma unroll
      for (int r = 0; r < 4; ++r) {
        int row = qt * 128 + w * 32 + mf * 16 + 4 * g + r;
        int col = nf * 16 + x;
        Ofin[((size_t)b * S_ + row) * (A_ * DA_) + a * DA_ + col] =
            (__bf16)(o_[mf][nf][r] * inv[r]);
      }
  }
}

// ---------------- kernel 5: output projection, bf16 MFMA ----------------
// grid (1024/128=8 n-tiles, 16384/128=128 m-tiles), block 256 (4 waves).
// Tile 128x128, K=256 in BK=64 steps. Wave owns 64x64 (4x4 frags).
__global__ __launch_bounds__(256) void k_oproj_mfma(const __bf16* __restrict__ Of,
                                                    const __bf16* __restrict__ WoT,
                                                    const float* __restrict__ bo,
                                                    float* __restrict__ Z) {
  __shared__ unsigned short As[128][72];
  __shared__ unsigned short Bs[128][72];
  const int nt = blockIdx.x, mt = blockIdx.y;
  const int t = threadIdx.x;
  const int w = t >> 6, l = t & 63, x = l & 15, g = l >> 4;
  const int MO = (w >> 1) * 64, NO = (w & 1) * 64;

  const unsigned short* Ofu = (const unsigned short*)Of;
  const unsigned short* Wu  = (const unsigned short*)WoT;

  f32x4 acc[4][4];
  #pragma unroll
  for (int mf = 0; mf < 4; ++mf)
    #pragma unroll
    for (int nf = 0; nf < 4; ++nf) acc[mf][nf] = (f32x4){0.f, 0.f, 0.f, 0.f};

  for (int k0 = 0; k0 < A_ * DA_; k0 += 64) {
    #pragma unroll
    for (int i = 0; i < 4; ++i) {
      int id = t + 256 * i;
      int row = id >> 3, ch = id & 7;
      u16x8 v = *(const u16x8*)(Ofu + ((size_t)(mt * 128 + row)) * (A_ * DA_) + k0 + ch * 8);
      *(u16x8*)&As[row][ch * 8] = v;
    }
    #pragma unroll
    for (int i = 0; i < 4; ++i) {
      int id = t + 256 * i;
      int row = id >> 3, ch = id & 7;
      u16x8 v = *(const u16x8*)(Wu + ((size_t)(nt * 128 + row)) * (A_ * DA_) + k0 + ch * 8);
      *(u16x8*)&Bs[row][ch * 8] = v;
    }
    __syncthreads();
    #pragma unroll
    for (int ks = 0; ks < 2; ++ks) {
      bf16x8 af[4], bfr[4];
      #pragma unroll
      for (int mf = 0; mf < 4; ++mf)
        af[mf] = *(const bf16x8*)&As[MO + mf * 16 + x][ks * 32 + g * 8];
      #pragma unroll
      for (int nf = 0; nf < 4; ++nf)
        bfr[nf] = *(const bf16x8*)&Bs[NO + nf * 16 + x][ks * 32 + g * 8];
      #pragma unroll
      for (int mf = 0; mf < 4; ++mf)
        #pragma unroll
        for (int nf = 0; nf < 4; ++nf)
          acc[mf][nf] = __builtin_amdgcn_mfma_f32_16x16x32_bf16(af[mf], bfr[nf], acc[mf][nf], 0, 0, 0);
    }
    __syncthreads();
  }

  #pragma unroll
  for (int nf = 0; nf < 4; ++nf) {
    const int n = nt * 128 + NO + nf * 16 + x;
    const float bval = bo[n];
    #pragma unroll
    for (int mf = 0; mf < 4; ++mf)
      #pragma unroll
      for (int r = 0; r < 4; ++r) {
        int row = mt * 128 + MO + mf * 16 + 4 * g + r;
        Z[(size_t)row * D_ + n] = acc[mf][nf][r] + bval;
      }
  }
}

extern "C" void kernel_launch(void* const* d_in, const int* in_sizes, int n_in,
                              void* d_out, int out_size, void* d_ws, size_t ws_size,
                              hipStream_t stream) {
  const float* x     = (const float*)d_in[0];
  const float* Wq    = (const float*)d_in[1];
  const float* bq    = (const float*)d_in[2];
  const float* Wk    = (const float*)d_in[3];
  const float* bk    = (const float*)d_in[4];
  const float* Wv    = (const float*)d_in[5];
  const float* bv    = (const float*)d_in[6];
  const float* Wr    = (const float*)d_in[7];
  const float* br    = (const float*)d_in[8];
  const float* gamma = (const float*)d_in[9];
  const float* beta  = (const float*)d_in[10];
  const float* Wo    = (const float*)d_in[11];
  const float* bo    = (const float*)d_in[12];
  float* Z = (float*)d_out;

  char* ws = (char*)d_ws;
  float*  partial = (float*)(ws + OFF_PARTIAL);
  int*    idx     = (int*)(ws + OFF_IDX);
  float*  dist    = (float*)(ws + OFF_DIST);
  __bf16* WoT     = (__bf16*)(ws + OFF_WOT);
  __bf16* xb      = (__bf16*)(ws + OFF_XB);
  __bf16* Wt      = (__bf16*)(ws + OFF_WT);
  __bf16* Q       = (__bf16*)(ws + OFF_Q);
  __bf16* K       = (__bf16*)(ws + OFF_K);
  __bf16* V       = (__bf16*)(ws + OFF_V);
  __bf16* Ofin    = (__bf16*)(ws + OFF_OFIN);

  k_partial<<<dim3(32, B_), 256, 0, stream>>>(x, partial, xb);
  k_wt<<<dim3(16, 16, 3), 256, 0, stream>>>(Wq, Wk, Wv, Wt);
  k_wto<<<dim3(16, 4), 256, 0, stream>>>(Wo, WoT);
  k_stats<<<B_, 256, 0, stream>>>(partial, Wr, br, gamma, beta, idx, dist);
  k_qkv_mfma<<<dim3(S_ / 128, B_ * A_), 256, 0, stream>>>(xb, Wt, bq, bk, bv, idx, Q, K, V);
  k_attn_mfma<<<dim3(S_ / 128, B_ * A_), 256, 0, stream>>>(Q, K, V, dist, Ofin);
  k_oproj_mfma<<<dim3(D_ / 128, (B_ * S_) / 128), 256, 0, stream>>>(Ofin, WoT, bo, Z);
}